// Round 4
// baseline (27.762 us; speedup 1.0000x reference)
//
#include <hip/hip_runtime.h>

#define N 512
#define D 128

// ws layout:
//   float  XT[2][128][512]   (512 KB)  transposed src/tgt
//   double partials[256]     (2 KB)    per-block v-sums
//   int    counter           (4 B)     last-block ticket

__device__ __forceinline__ double wave_reduce_add(double v) {
    #pragma unroll
    for (int off = 32; off > 0; off >>= 1)
        v += __shfl_down(v, off, 64);
    return v;
}

// K0: LDS-tiled transpose. 128 blocks: m(2) x dtile(4) x jtile(16), 32x32 tiles.
// Also zeroes the ticket counter (stream-ordered before K1).
__global__ __launch_bounds__(256) void gw_transpose(
    const float* __restrict__ src, const float* __restrict__ tgt,
    float* __restrict__ XT, int* __restrict__ counter)
{
    if (blockIdx.x == 0 && threadIdx.x == 0) *counter = 0;

    __shared__ float ld[32][33];
    const int b  = blockIdx.x;
    const int m  = b >> 6;
    const int dt = (b >> 4) & 3;
    const int jt = b & 15;
    const float* X = m ? tgt : src;
    float* XTm = XT + m * (D * N);

    const int t = threadIdx.x;
    const int c = t & 31;
    const int r = t >> 5;

    #pragma unroll
    for (int p = 0; p < 4; ++p) {
        int jr = r + p * 8;
        ld[jr][c] = X[(jt * 32 + jr) * D + dt * 32 + c];   // coalesced read
    }
    __syncthreads();
    #pragma unroll
    for (int p = 0; p < 4; ++p) {
        int dr = r + p * 8;
        XTm[(dt * 32 + dr) * N + jt * 32 + c] = ld[c][dr]; // conflict-free, coalesced write
    }
}

// K1: 256 blocks x 512 threads. Block b owns rows {2b, 2b+1} of BOTH matrices,
// full j-range (thread tid = column j). Fused finalize via last-block ticket.
__global__ __launch_bounds__(512) void gw_distfin(
    const float* __restrict__ src, const float* __restrict__ tgt,
    const float* __restrict__ XT,
    double* __restrict__ partials, int* __restrict__ counter,
    float* __restrict__ out)
{
    const int b   = blockIdx.x;
    const int tid = threadIdx.x;       // j
    const int i0  = 2 * b;
    const int i1  = i0 + 1;

    const float* XTs = XT;             // [d][j]
    const float* XTt = XT + D * N;
    const float* s0  = src + i0 * D;   // wave-uniform rows -> scalar loads
    const float* s1  = src + i1 * D;
    const float* t0  = tgt + i0 * D;
    const float* t1  = tgt + i1 * D;

    float as0 = 0.f, as1 = 0.f, at0 = 0.f, at1 = 0.f;
    #pragma unroll 8
    for (int d = 0; d < D; ++d) {
        float vs = XTs[d * N + tid];   // coalesced: lane stride 4B
        float vt = XTt[d * N + tid];
        float e;
        e = s0[d] - vs; as0 += e * e;
        e = s1[d] - vs; as1 += e * e;
        e = t0[d] - vt; at0 += e * e;
        e = t1[d] - vt; at1 += e * e;
    }

    // 8 block-reduced quantities (double): rs_s0, rs_s1, rs_t0, rs_t1,
    //                                      ss_s0, ss_s1, ss_t0, ss_t1
    double q[8];
    q[0] = (double)as0; q[1] = (double)as1;
    q[2] = (double)at0; q[3] = (double)at1;
    q[4] = (double)as0 * (double)as0;
    q[5] = (double)as1 * (double)as1;
    q[6] = (double)at0 * (double)at0;
    q[7] = (double)at1 * (double)at1;

    __shared__ double red[8][8];       // [wave][quantity]
    __shared__ int islast;
    const int wave = tid >> 6;
    const int lane = tid & 63;
    #pragma unroll
    for (int k = 0; k < 8; ++k) {
        double v = wave_reduce_add(q[k]);
        if (lane == 0) red[wave][k] = v;
    }
    __syncthreads();

    if (tid == 0) {
        double s[8];
        #pragma unroll
        for (int k = 0; k < 8; ++k) {
            double acc = 0.0;
            #pragma unroll
            for (int w = 0; w < 8; ++w) acc += red[w][k];
            s[k] = acc;
        }
        // v_i = N*(ss_s + ss_t) - 2*rs_s*rs_t, for i0 and i1
        double v0 = (double)N * (s[4] + s[6]) - 2.0 * s[0] * s[2];
        double v1 = (double)N * (s[5] + s[7]) - 2.0 * s[1] * s[3];
        partials[b] = v0 + v1;
        __threadfence();
        int ticket = atomicAdd(counter, 1);
        islast = (ticket == (int)gridDim.x - 1);
    }
    __syncthreads();

    if (islast) {
        __threadfence();               // acquire: all partials visible
        double p = (tid < 256) ? partials[tid] : 0.0;
        p = wave_reduce_add(p);
        if (lane == 0) red[wave][0] = p;
        __syncthreads();
        if (tid == 0) {
            double total = 0.0;
            #pragma unroll
            for (int w = 0; w < 8; ++w) total += red[w][0];
            out[0] = (float)(total / ((double)N * (double)N));
        }
    }
}

extern "C" void kernel_launch(void* const* d_in, const int* in_sizes, int n_in,
                              void* d_out, int out_size, void* d_ws, size_t ws_size,
                              hipStream_t stream) {
    const float* src = (const float*)d_in[0];
    const float* tgt = (const float*)d_in[1];
    float* out = (float*)d_out;

    float*  XT       = (float*)d_ws;
    double* partials = (double*)((char*)d_ws + 2 * D * N * sizeof(float));
    int*    counter  = (int*)((char*)d_ws + 2 * D * N * sizeof(float) + 256 * sizeof(double));

    gw_transpose<<<dim3(128), dim3(256), 0, stream>>>(src, tgt, XT, counter);
    gw_distfin  <<<dim3(256), dim3(512), 0, stream>>>(src, tgt, XT, partials, counter, out);
}

// Round 5
// 23.902 us; speedup vs baseline: 1.1615x; 1.1615x over previous
//
#include <hip/hip_runtime.h>

#define N 512
#define D 128

// ws layout:
//   float  XT[2][128][512]            512 KB  transposed src/tgt (planar)
//   ull    rs_bits[2][512]            8 KB    complete row-sums (double bits)
//   ull    ss_bits[2][512]            8 KB    complete row sum-of-squares
//   int    counter                    4 B     last-block ticket

__device__ __forceinline__ double wave_reduce_add(double v) {
    #pragma unroll
    for (int off = 32; off > 0; off >>= 1)
        v += __shfl_down(v, off, 64);
    return v;
}

// K0: LDS-tiled transpose. 128 blocks: m(2) x dtile(4) x jtile(16), 32x32 tiles.
// Also zeroes the ticket counter (stream-ordered before K1).
__global__ __launch_bounds__(256) void gw_transpose(
    const float* __restrict__ src, const float* __restrict__ tgt,
    float* __restrict__ XT, int* __restrict__ counter)
{
    if (blockIdx.x == 0 && threadIdx.x == 0) *counter = 0;

    __shared__ float ld[32][33];
    const int b  = blockIdx.x;
    const int m  = b >> 6;
    const int dt = (b >> 4) & 3;
    const int jt = b & 15;
    const float* X = m ? tgt : src;
    float* XTm = XT + m * (D * N);

    const int t = threadIdx.x;
    const int c = t & 31;
    const int r = t >> 5;

    #pragma unroll
    for (int p = 0; p < 4; ++p) {
        int jr = r + p * 8;
        ld[jr][c] = X[(jt * 32 + jr) * D + dt * 32 + c];   // coalesced read
    }
    __syncthreads();
    #pragma unroll
    for (int p = 0; p < 4; ++p) {
        int dr = r + p * 8;
        XTm[(dt * 32 + dr) * N + jt * 32 + c] = ld[c][dr]; // conflict-free, coalesced write
    }
}

// K1: 256 blocks x 512 threads. Block b = (m = b>>7, iq = b&127) owns rows
// i0..i0+3 of ONE matrix over the FULL j-range (thread tid = j). Writes
// complete rs/ss for its 4 rows, then last block finalizes. No fences:
// release ordering via atomicExch completion (returns consumed by asm sink).
__global__ __launch_bounds__(512) void gw_distfin(
    const float* __restrict__ src, const float* __restrict__ tgt,
    const float* __restrict__ XT,
    unsigned long long* __restrict__ rs_bits,
    unsigned long long* __restrict__ ss_bits,
    int* __restrict__ counter, float* __restrict__ out)
{
    const int b   = blockIdx.x;
    const int m   = b >> 7;
    const int iq  = b & 127;
    const int i0  = iq * 4;
    const int tid = threadIdx.x;   // j

    const float* X   = m ? tgt : src;
    const float* XTm = XT + m * (D * N);
    const float* r0  = X + (i0 + 0) * D;   // wave-uniform rows -> scalar loads
    const float* r1  = X + (i0 + 1) * D;
    const float* r2  = X + (i0 + 2) * D;
    const float* r3  = X + (i0 + 3) * D;

    float a0 = 0.f, a1 = 0.f, a2 = 0.f, a3 = 0.f;
    #pragma unroll 8
    for (int d = 0; d < D; ++d) {
        float v = XTm[d * N + tid];        // coalesced: lane stride 4B
        float e;
        e = r0[d] - v; a0 += e * e;
        e = r1[d] - v; a1 += e * e;
        e = r2[d] - v; a2 += e * e;
        e = r3[d] - v; a3 += e * e;
    }

    // one pair per (thread, i): q are single dist / dist^2 values (exact f32),
    // the j-sum happens entirely in double below.
    double q[8];
    q[0] = (double)a0; q[1] = (double)a1; q[2] = (double)a2; q[3] = (double)a3;
    q[4] = (double)a0 * (double)a0;
    q[5] = (double)a1 * (double)a1;
    q[6] = (double)a2 * (double)a2;
    q[7] = (double)a3 * (double)a3;

    __shared__ double red[8][8];           // [wave][quantity]
    __shared__ int islast;
    const int wave = tid >> 6;
    const int lane = tid & 63;
    #pragma unroll
    for (int k = 0; k < 8; ++k) {
        double v = wave_reduce_add(q[k]);
        if (lane == 0) red[wave][k] = v;
    }
    __syncthreads();

    if (tid == 0) {
        unsigned long long olds[8];
        #pragma unroll
        for (int k = 0; k < 8; ++k) {
            double rsk = 0.0, ssk = 0.0;
            // (loop split below keeps k meaning: 0..3 rs, 4..7 ss)
            (void)rsk; (void)ssk;
        }
        #pragma unroll
        for (int k = 0; k < 4; ++k) {
            double rs = 0.0, ss = 0.0;
            #pragma unroll
            for (int w = 0; w < 8; ++w) { rs += red[w][k]; ss += red[w][k + 4]; }
            olds[k]     = atomicExch(&rs_bits[m * N + i0 + k], (unsigned long long)__double_as_longlong(rs));
            olds[k + 4] = atomicExch(&ss_bits[m * N + i0 + k], (unsigned long long)__double_as_longlong(ss));
        }
        // consume returned values: forces s_waitcnt vmcnt(0) -> all 8 atomics
        // completed at the device coherence point before the ticket increments.
        asm volatile("" :: "v"(olds[0]), "v"(olds[1]), "v"(olds[2]), "v"(olds[3]),
                           "v"(olds[4]), "v"(olds[5]), "v"(olds[6]), "v"(olds[7]));
        int ticket = atomicAdd(counter, 1);
        islast = (ticket == (int)gridDim.x - 1);
    }
    __syncthreads();

    if (islast) {
        // coherent reads of the published doubles (device-scope RMW, add 0)
        const int i = tid;
        double rs_s = __longlong_as_double((long long)atomicAdd(&rs_bits[0 * N + i], 0ULL));
        double rs_t = __longlong_as_double((long long)atomicAdd(&rs_bits[1 * N + i], 0ULL));
        double ss_s = __longlong_as_double((long long)atomicAdd(&ss_bits[0 * N + i], 0ULL));
        double ss_t = __longlong_as_double((long long)atomicAdd(&ss_bits[1 * N + i], 0ULL));

        double v = (double)N * (ss_s + ss_t) - 2.0 * rs_s * rs_t;
        v = wave_reduce_add(v);
        if (lane == 0) red[wave][0] = v;
        __syncthreads();
        if (tid == 0) {
            double total = 0.0;
            #pragma unroll
            for (int w = 0; w < 8; ++w) total += red[w][0];
            out[0] = (float)(total / ((double)N * (double)N));
        }
    }
}

extern "C" void kernel_launch(void* const* d_in, const int* in_sizes, int n_in,
                              void* d_out, int out_size, void* d_ws, size_t ws_size,
                              hipStream_t stream) {
    const float* src = (const float*)d_in[0];
    const float* tgt = (const float*)d_in[1];
    float* out = (float*)d_out;

    char* w = (char*)d_ws;
    float*              XT      = (float*)w;                                   // 512 KB
    unsigned long long* rs_bits = (unsigned long long*)(w + 2 * D * N * 4);    // 8 KB
    unsigned long long* ss_bits = (unsigned long long*)(w + 2 * D * N * 4 + 2 * N * 8);
    int*                counter = (int*)(w + 2 * D * N * 4 + 4 * N * 8);

    gw_transpose<<<dim3(128), dim3(256), 0, stream>>>(src, tgt, XT, counter);
    gw_distfin  <<<dim3(256), dim3(512), 0, stream>>>(src, tgt, XT, rs_bits, ss_bits,
                                                      counter, out);
}